// Round 12
// baseline (1110.073 us; speedup 1.0000x reference)
//
#include <hip/hip_runtime.h>
#include <math.h>

// Round 12: no-LDS conv kernels + register double-buffering (ILP) to hide
// L2 latency at grid-limited occupancy. Weights via wave-uniform s_load from
// pre-transposed [k][c]; acts coalesced (lane==batch); XCD-friendly linear
// grid (id = ct*64 + bblk). Window: x 231..255 -> h0(21) -> y0(9) -> h1(5)
// -> y1@255 -> head. ~12.6 GFLOP.

#define R     4096
#define CIN   30
#define LSEQ  256
#define C1    100
#define C2    200
#define KW    5
#define T0    231
#define WIN   25
#define NU0   21
#define NJ0   9
#define NT1   5

// ---- workspace layout (float offsets). Total 3884 rows x 4096 = 63.6 MB ----
#define OFF_HW1T  0          // 160000
#define OFF_WT10  160000     // 15000   w1_0T [150][100]
#define OFF_WT20  175000     // 50000   w2_0T [500][100]
#define OFF_WDT0  225000     // 3000    wd_0T [30][100]
#define OFF_WT11  228000     // 100000  w1_1T [500][200]
#define OFF_WT21  328000     // 200000  w2_1T [1000][200]
#define OFF_WDT1  528000     // 20000   wd_1T [100][200]
#define ROW_XT    134        // 750 rows (xT)
#define ROW_H0T   884        // 2100 rows
#define ROW_Y0T   2984       // 900 rows -> ends 3884
#define ROW_H1T   134        // 1000 rows, aliases xT+h0T head (dead by k3)
#define ROW_FEAT  1134       // 200 rows, inside dead h0T (k4a runs after k2)

// ------ K_prep: fused transposes (dst-linear; sources small + cached) -------
#define NPREP 548000
__global__ __launch_bounds__(256) void k_prep(
    const float* __restrict__ hw1, const float* __restrict__ w1_0,
    const float* __restrict__ w2_0, const float* __restrict__ wd_0,
    const float* __restrict__ w1_1, const float* __restrict__ w2_1,
    const float* __restrict__ wd_1, float* __restrict__ ws) {
  int idx = blockIdx.x * 256 + threadIdx.x;
  if (idx >= NPREP) return;
  if (idx < 160000) {  // hw1T[h][d][o] = hw1[h][o][d]
    const int h = idx / 20000, r = idx - h * 20000;
    const int d = r / C1, o = r - d * C1;
    ws[OFF_HW1T + idx] = hw1[h * 20000 + o * C2 + d];
  } else if (idx < 175000) {  // wT10[kk][c]
    const int r = idx - 160000, kk = r / C1, c = r - kk * C1;
    ws[idx] = w1_0[c * (CIN * KW) + kk];
  } else if (idx < 225000) {  // wT20[kk][c]
    const int r = idx - 175000, kk = r / C1, c = r - kk * C1;
    ws[idx] = w2_0[c * (C1 * KW) + kk];
  } else if (idx < 228000) {  // wdT0[ci][c]
    const int r = idx - 225000, ci = r / C1, c = r - ci * C1;
    ws[idx] = wd_0[c * CIN + ci];
  } else if (idx < 328000) {  // wT11[kk][c]
    const int r = idx - 228000, kk = r / C2, c = r - kk * C2;
    ws[idx] = w1_1[c * (C1 * KW) + kk];
  } else if (idx < 528000) {  // wT21[kk][c]
    const int r = idx - 328000, kk = r / C2, c = r - kk * C2;
    ws[idx] = w2_1[(size_t)c * (C2 * KW) + kk];
  } else {  // wdT1[ci][c]
    const int r = idx - 528000, ci = r / C2, c = r - ci * C2;
    ws[idx] = wd_1[c * C1 + ci];
  }
}

// ---------------- K_tr: transpose x window -> xT[(ci*25+u)][b] --------------
__global__ __launch_bounds__(256) void k_tr(const float* __restrict__ x,
                                            float* __restrict__ xT) {
  const int l = threadIdx.x & 63, wv = threadIdx.x >> 6;
  const int b = blockIdx.x * 64 + l;
  const float* xb = x + (size_t)b * (CIN * LSEQ) + T0;
  for (int r2 = wv; r2 < 150; r2 += 4) {
    const int r = blockIdx.y * 150 + r2;
    const int ci = r / WIN, u = r - ci * WIN;
    xT[(size_t)r * R + b] = xb[ci * LSEQ + u];
  }
}

// ------ K1: h0T = relu(conv1_0). 2 ch/thread, scalar weights, ci-dbuf -------
__global__ __launch_bounds__(256, 4) void k1(const float* __restrict__ xT,
                                             const float* __restrict__ wT10,
                                             const float* __restrict__ b1,
                                             float* __restrict__ h0T) {
  const int id = blockIdx.x;
  const int bblk = id & 63, ct = id >> 6;  // 13 ctiles of 8 ch
  const int tid = threadIdx.x;
  const int l = tid & 63, wv = tid >> 6;
  const int b = bblk * 64 + l;
  int c0 = ct * 8 + __builtin_amdgcn_readfirstlane(wv) * 2;
  c0 = (c0 > C1 - 2) ? C1 - 2 : c0;  // clamp (dup writes identical)
  float acc0[NU0], acc1[NU0];
  const float bi0 = b1[c0], bi1 = b1[c0 + 1];
#pragma unroll
  for (int u = 0; u < NU0; ++u) { acc0[u] = bi0; acc1[u] = bi1; }
#define K1_LOAD(dst, ci_) { _Pragma("unroll") \
  for (int u = 0; u < WIN; ++u) dst[u] = xT[(size_t)((ci_) * WIN + u) * R + b]; }
#define K1_FMA(src, ci_) { _Pragma("unroll") \
  for (int k = 0; k < KW; ++k) { \
    const float* wr = wT10 + ((ci_) * KW + k) * C1 + c0; \
    const float w0 = wr[0], w1v = wr[1]; \
    _Pragma("unroll") \
    for (int u = 0; u < NU0; ++u) { \
      acc0[u] = fmaf(src[u + k], w0, acc0[u]); \
      acc1[u] = fmaf(src[u + k], w1v, acc1[u]); } } }
  float xrA[WIN], xrB[WIN];
  K1_LOAD(xrA, 0);
  for (int ci = 0; ci < CIN; ci += 2) {  // CIN=30 even
    K1_LOAD(xrB, ci + 1);
    K1_FMA(xrA, ci);
    if (ci + 2 < CIN) K1_LOAD(xrA, ci + 2);
    K1_FMA(xrB, ci + 1);
  }
#pragma unroll
  for (int u = 0; u < NU0; ++u) {
    h0T[(size_t)(c0 * NU0 + u) * R + b] = fmaxf(acc0[u], 0.f);
    h0T[(size_t)((c0 + 1) * NU0 + u) * R + b] = fmaxf(acc1[u], 0.f);
  }
}

// --- K2: y0T = relu(relu(conv2_0) + wd_0*x + bd_0). 2 ch/thread, ci-dbuf ----
__global__ __launch_bounds__(256, 4) void k2(const float* __restrict__ xT,
                                             const float* __restrict__ h0T,
                                             const float* __restrict__ wT20,
                                             const float* __restrict__ b2,
                                             const float* __restrict__ wdT0,
                                             const float* __restrict__ bd,
                                             float* __restrict__ y0T) {
  const int id = blockIdx.x;
  const int bblk = id & 63, ct = id >> 6;
  const int tid = threadIdx.x;
  const int l = tid & 63, wv = tid >> 6;
  const int b = bblk * 64 + l;
  int c0 = ct * 8 + __builtin_amdgcn_readfirstlane(wv) * 2;
  c0 = (c0 > C1 - 2) ? C1 - 2 : c0;
  float acc0[NJ0], acc1[NJ0];
  {
    const float bA = b2[c0], bB = b2[c0 + 1];
#pragma unroll
    for (int j = 0; j < NJ0; ++j) { acc0[j] = bA; acc1[j] = bB; }
  }
  // main conv: h0 reads double-buffered across ci
#define K2_LOAD(dst, ci_) { _Pragma("unroll") \
  for (int u = 0; u < NU0; ++u) dst[u] = h0T[(size_t)((ci_) * NU0 + u) * R + b]; }
#define K2_FMA(src, ci_) { _Pragma("unroll") \
  for (int k = 0; k < KW; ++k) { \
    const float* wr = wT20 + ((ci_) * KW + k) * C1 + c0; \
    const float w0 = wr[0], w1v = wr[1]; \
    _Pragma("unroll") \
    for (int j = 0; j < NJ0; ++j) { \
      acc0[j] = fmaf(src[2 * j + k], w0, acc0[j]); \
      acc1[j] = fmaf(src[2 * j + k], w1v, acc1[j]); } } }
  float hrA[NU0], hrB[NU0];
  K2_LOAD(hrA, 0);
  for (int ci = 0; ci < C1; ci += 2) {  // C1=100 even
    K2_LOAD(hrB, ci + 1);
    K2_FMA(hrA, ci);
    if (ci + 2 < C1) K2_LOAD(hrA, ci + 2);
    K2_FMA(hrB, ci + 1);
  }
  // residual from x (rows ci*25+8+2j)
  float rac0[NJ0], rac1[NJ0];
  {
    const float dA = bd[c0], dB = bd[c0 + 1];
#pragma unroll
    for (int j = 0; j < NJ0; ++j) { rac0[j] = dA; rac1[j] = dB; }
  }
#pragma unroll 2
  for (int ci = 0; ci < CIN; ++ci) {
    float xr[NJ0];
#pragma unroll
    for (int j = 0; j < NJ0; ++j) xr[j] = xT[(size_t)(ci * WIN + 8 + 2 * j) * R + b];
    const float* wr = wdT0 + ci * C1 + c0;
    const float w0 = wr[0], w1v = wr[1];
#pragma unroll
    for (int j = 0; j < NJ0; ++j) {
      rac0[j] = fmaf(xr[j], w0, rac0[j]);
      rac1[j] = fmaf(xr[j], w1v, rac1[j]);
    }
  }
#pragma unroll
  for (int j = 0; j < NJ0; ++j) {
    y0T[(size_t)(c0 * NJ0 + j) * R + b] = fmaxf(fmaxf(acc0[j], 0.f) + rac0[j], 0.f);
    y0T[(size_t)((c0 + 1) * NJ0 + j) * R + b] = fmaxf(fmaxf(acc1[j], 0.f) + rac1[j], 0.f);
  }
}

// ------- K3: h1T = relu(conv1_1 dil2). 2 ch/thread, scalar w, ci-dbuf -------
__global__ __launch_bounds__(256, 4) void k3(const float* __restrict__ y0T,
                                             const float* __restrict__ wT11,
                                             const float* __restrict__ b1,
                                             float* __restrict__ h1T) {
  const int id = blockIdx.x;
  const int bblk = id & 63, ct = id >> 6;  // 25 ctiles of 8 -> 200 exact
  const int tid = threadIdx.x;
  const int l = tid & 63, wv = tid >> 6;
  const int b = bblk * 64 + l;
  const int c0 = ct * 8 + __builtin_amdgcn_readfirstlane(wv) * 2;
  float acc0[NT1], acc1[NT1];
  const float bi0 = b1[c0], bi1 = b1[c0 + 1];
#pragma unroll
  for (int t = 0; t < NT1; ++t) { acc0[t] = bi0; acc1[t] = bi1; }
#define K3_LOAD(dst, ci_) { _Pragma("unroll") \
  for (int u = 0; u < NJ0; ++u) dst[u] = y0T[(size_t)((ci_) * NJ0 + u) * R + b]; }
#define K3_FMA(src, ci_) { _Pragma("unroll") \
  for (int k = 0; k < KW; ++k) { \
    const float* wr = wT11 + ((ci_) * KW + k) * C2 + c0; \
    const float w0 = wr[0], w1v = wr[1]; \
    _Pragma("unroll") \
    for (int t = 0; t < NT1; ++t) { \
      acc0[t] = fmaf(src[t + k], w0, acc0[t]); \
      acc1[t] = fmaf(src[t + k], w1v, acc1[t]); } } }
  float yrA[NJ0], yrB[NJ0];
  K3_LOAD(yrA, 0);
  for (int ci = 0; ci < C1; ci += 2) {
    K3_LOAD(yrB, ci + 1);
    K3_FMA(yrA, ci);
    if (ci + 2 < C1) K3_LOAD(yrA, ci + 2);
    K3_FMA(yrB, ci + 1);
  }
#pragma unroll
  for (int t = 0; t < NT1; ++t) {
    h1T[(size_t)(c0 * NT1 + t) * R + b] = fmaxf(acc0[t], 0.f);
    h1T[(size_t)((c0 + 1) * NT1 + t) * R + b] = fmaxf(acc1[t], 0.f);
  }
}

// -- K4a: featT = relu(relu(conv2_1@255)+res). 4 ch/thread, kk-dbuf GEMM -----
__global__ __launch_bounds__(256, 4) void k4a(const float* __restrict__ h1T,
                                              const float* __restrict__ y0T,
                                              const float* __restrict__ wT21,
                                              const float* __restrict__ b2,
                                              const float* __restrict__ wdT1,
                                              const float* __restrict__ bd,
                                              float* __restrict__ featT) {
  const int id = blockIdx.x;
  const int bblk = id & 63, ct = id >> 6;  // 13 ctiles of 16 ch
  const int tid = threadIdx.x;
  const int l = tid & 63, wv = tid >> 6;
  const int b = bblk * 64 + l;
  int c0 = ct * 16 + __builtin_amdgcn_readfirstlane(wv) * 4;
  c0 = (c0 > C2 - 4) ? C2 - 4 : c0;  // clamp (dup writes identical)
  float acc[4], rs[4];
#pragma unroll
  for (int m = 0; m < 4; ++m) { acc[m] = b2[c0 + m]; rs[m] = bd[c0 + m]; }
#define K4_LOAD(dst, base) { _Pragma("unroll") \
  for (int i = 0; i < 8; ++i) dst[i] = h1T[(size_t)((base) + i) * R + b]; }
#define K4_FMA(src, base) { _Pragma("unroll") \
  for (int i = 0; i < 8; ++i) { \
    const float* wr = wT21 + ((base) + i) * C2 + c0; \
    acc[0] = fmaf(src[i], wr[0], acc[0]); acc[1] = fmaf(src[i], wr[1], acc[1]); \
    acc[2] = fmaf(src[i], wr[2], acc[2]); acc[3] = fmaf(src[i], wr[3], acc[3]); } }
  float aA[8], aB[8];
  K4_LOAD(aA, 0);
  for (int kk = 0; kk + 16 <= C2 * KW; kk += 16) {  // 1000 = 62*16 + 8
    K4_LOAD(aB, kk + 8);
    K4_FMA(aA, kk);
    if (kk + 16 < C2 * KW) K4_LOAD(aA, kk + 16);
    K4_FMA(aB, kk + 8);
  }
  K4_FMA(aA, 992);  // tail rows 992..999 (loaded in last iteration)
  // residual: y0 @ t=255 (rows ci*9+8), wd_1T
#pragma unroll 4
  for (int ci = 0; ci < C1; ++ci) {
    const float a = y0T[(size_t)(ci * NJ0 + 8) * R + b];
    const float* wr = wdT1 + ci * C2 + c0;
    rs[0] = fmaf(a, wr[0], rs[0]); rs[1] = fmaf(a, wr[1], rs[1]);
    rs[2] = fmaf(a, wr[2], rs[2]); rs[3] = fmaf(a, wr[3], rs[3]);
  }
#pragma unroll
  for (int m = 0; m < 4; ++m)
    featT[(size_t)(c0 + m) * R + b] = fmaxf(fmaxf(acc[m], 0.f) + rs[m], 0.f);
}

// -------- K4b: per-batch head, transposed W1 (coalesced), wave=item ---------
__global__ __launch_bounds__(256) void k4b(const float* __restrict__ featT,
                                           const int* __restrict__ labels,
                                           const float* __restrict__ hw1T,
                                           const float* __restrict__ hb1,
                                           const float* __restrict__ hw2,
                                           const float* __restrict__ hb2,
                                           float* __restrict__ out) {
  __shared__ float fs[4][C2];
  const int tid = threadIdx.x;
  const int b0 = blockIdx.x * 4;
  for (int idx = tid; idx < 4 * C2; idx += 256) {
    const int c = idx >> 2, bi = idx & 3;
    fs[bi][c] = featT[(size_t)c * R + b0 + bi];
  }
  __syncthreads();
  const int l = tid & 63, wv = tid >> 6;
  const int b = b0 + wv;
  const int task = labels[b];
  const float* Wt = hw1T + (size_t)task * (C1 * C2);  // [d][o]
  const float* fp = fs[wv];
  float a0 = hb1[task * C1 + l];
  float a1 = (l < C1 - 64) ? hb1[task * C1 + 64 + l] : 0.f;
  for (int d = 0; d < C2; ++d) {
    const float fd = fp[d];
    const float* row = Wt + d * C1;
    a0 = fmaf(fd, row[l], a0);
    if (l < C1 - 64) a1 = fmaf(fd, row[64 + l], a1);
  }
  float p = tanhf(a0) * hw2[task * C1 + l];
  if (l < C1 - 64) p = fmaf(tanhf(a1), hw2[task * C1 + 64 + l], p);
#pragma unroll
  for (int off = 32; off > 0; off >>= 1) p += __shfl_down(p, off, 64);
  if (l == 0) out[b] = p + hb2[task];
}

extern "C" void kernel_launch(void* const* d_in, const int* in_sizes, int n_in,
                              void* d_out, int out_size, void* d_ws, size_t ws_size,
                              hipStream_t stream) {
  const float* x    = (const float*)d_in[0];
  const int* labels = (const int*)d_in[1];
  const float* w1_0 = (const float*)d_in[2];
  const float* b1_0 = (const float*)d_in[3];
  const float* w2_0 = (const float*)d_in[4];
  const float* b2_0 = (const float*)d_in[5];
  const float* wd_0 = (const float*)d_in[6];
  const float* bd_0 = (const float*)d_in[7];
  const float* w1_1 = (const float*)d_in[8];
  const float* b1_1 = (const float*)d_in[9];
  const float* w2_1 = (const float*)d_in[10];
  const float* b2_1 = (const float*)d_in[11];
  const float* wd_1 = (const float*)d_in[12];
  const float* bd_1 = (const float*)d_in[13];
  const float* hw1  = (const float*)d_in[14];
  const float* hb1  = (const float*)d_in[15];
  const float* hw2  = (const float*)d_in[16];
  const float* hb2  = (const float*)d_in[17];
  float* out = (float*)d_out;

  float* ws    = (float*)d_ws;
  float* hw1T  = ws + OFF_HW1T;
  float* wT10  = ws + OFF_WT10;
  float* wT20  = ws + OFF_WT20;
  float* wdT0  = ws + OFF_WDT0;
  float* wT11  = ws + OFF_WT11;
  float* wT21  = ws + OFF_WT21;
  float* wdT1  = ws + OFF_WDT1;
  float* xT    = ws + (size_t)ROW_XT * R;
  float* h0T   = ws + (size_t)ROW_H0T * R;
  float* y0T   = ws + (size_t)ROW_Y0T * R;
  float* h1T   = ws + (size_t)ROW_H1T * R;   // aliases xT+h0T head (dead by k3)
  float* featT = ws + (size_t)ROW_FEAT * R;  // inside dead h0T (k4a after k2)

  hipLaunchKernelGGL(k_prep, dim3((NPREP + 255) / 256), dim3(256), 0, stream,
                     hw1, w1_0, w2_0, wd_0, w1_1, w2_1, wd_1, ws);
  hipLaunchKernelGGL(k_tr, dim3(64, 5), dim3(256), 0, stream, x, xT);
  // XCD swizzle: linear id = ct*64 + bblk -> id%8 == bblk%8 (ctiles co-XCD)
  hipLaunchKernelGGL(k1, dim3(13 * 64), dim3(256), 0, stream, xT, wT10, b1_0, h0T);
  hipLaunchKernelGGL(k2, dim3(13 * 64), dim3(256), 0, stream, xT, h0T, wT20, b2_0, wdT0, bd_0, y0T);
  hipLaunchKernelGGL(k3, dim3(25 * 64), dim3(256), 0, stream, y0T, wT11, b1_1, h1T);
  hipLaunchKernelGGL(k4a, dim3(13 * 64), dim3(256), 0, stream, h1T, y0T, wT21, b2_1, wdT1, bd_1, featT);
  hipLaunchKernelGGL(k4b, dim3(1024), dim3(256), 0, stream, featT, labels,
                     hw1T, hb1, hw2, hb2, out);
}